// Round 3
// baseline (394.175 us; speedup 1.0000x reference)
//
#include <hip/hip_runtime.h>

// MultiBoxLoss_four_corners — B=64, P=8732, C=81, NEG_POS_RATIO=3
// Outputs: (loss_l/N, loss_c/N, loss_four_corners/N) -> d_out[0..2] (f32)
//
// R5: LDS staging abandoned (R3 serial copy / R4 DMA both latency-bound:
// depth-1 prefetch + block lockstep barriers, compute << HBM latency).
// Now: one WAVE per conf row. Lane l reads row[l] and row[17+l] — two
// coalesced 256B loads, no LDS, no barriers. exp-sum via 6 shfl_xor,
// row[tgt] via uniform shfl. Next row's loads prefetched under current
// row's reduce; 32 waves/CU of independent streams hide latency.

#define NB 64
#define NP 8732
#define NC 81
constexpr int BP = NB * NP;              // 558848
constexpr int PBLK = (NP + 255) / 256;   // 35 blocks per batch (tail 28)

__device__ inline float sl1(float d) {
    d = fabsf(d);
    return d < 1.0f ? 0.5f * d * d : d - 0.5f;
}

// ws layout: ce[BP] | acc[2] | npos_b[64](int) | spos_b[64] | sneg_b[64] | loss_c_b[64]
__global__ void k_init(float* acc_area) {
    if (threadIdx.x < 194) acc_area[threadIdx.x] = 0.0f;
}

__global__ __launch_bounds__(256) void k_main(
    const float* __restrict__ loc_data, const float* __restrict__ conf_data,
    const float* __restrict__ fc_data,  const float* __restrict__ loc_t,
    const float* __restrict__ fc_t,     const int* __restrict__ conf_t,
    float* __restrict__ ce, float* __restrict__ acc,
    int* __restrict__ npos_b, float* __restrict__ spos_b, float* __restrict__ sneg_b)
{
    const int b  = blockIdx.y;
    const int t  = threadIdx.x;
    const int p0 = blockIdx.x << 8;

    __shared__ int   tgt_s[256];
    __shared__ float red[4][5];

    float l_sum = 0.0f, f_sum = 0.0f, sp = 0.0f, sn = 0.0f;
    int np = 0;

    // ---- per-prior smooth-L1 (coalesced float4) + stash targets ----
    {
        const int p = p0 + t;
        int tgt = 0;
        if (p < NP) {
            const size_t g = (size_t)b * NP + p;
            tgt = conf_t[g];
            const float posf = (tgt > 0) ? 1.0f : 0.0f;
            np = (tgt > 0) ? 1 : 0;
            float4 a4  = ((const float4*)loc_data)[g];
            float4 a4t = ((const float4*)loc_t)[g];
            l_sum = (sl1(a4.x - a4t.x) + sl1(a4.y - a4t.y) +
                     sl1(a4.z - a4t.z) + sl1(a4.w - a4t.w)) * posf;
            float4 c0 = ((const float4*)fc_data)[2 * g];
            float4 c1 = ((const float4*)fc_data)[2 * g + 1];
            float4 d0 = ((const float4*)fc_t)[2 * g];
            float4 d1 = ((const float4*)fc_t)[2 * g + 1];
            f_sum = (sl1(c0.x - d0.x) + sl1(c0.y - d0.y) + sl1(c0.z - d0.z) + sl1(c0.w - d0.w) +
                     sl1(c1.x - d1.x) + sl1(c1.y - d1.y) + sl1(c1.z - d1.z) + sl1(c1.w - d1.w)) * posf;
        }
        tgt_s[t] = tgt;
    }
    __syncthreads();

    // ---- CE: one wave per row, coalesced direct loads, no LDS staging ----
    // Row = 81 floats. Lane l covers elems {l} and {17+l} (17..63 dup-loaded;
    // duplicate exp masked by lane>=47). Both loads in-bounds, coalesced.
    const int wave = t >> 6, lane = t & 63;
    const int rbase = p0 + (wave << 6);               // this wave's first row
    const int rs = min(64, max(0, NP - rbase));       // rows this wave owns
    float v_ce = 0.0f;

    if (rs > 0) {
        const float* rowp = conf_data + ((size_t)b * NP + rbase) * (size_t)NC;
        float a0 = rowp[lane];
        float a1 = rowp[17 + lane];
        int   tg = tgt_s[wave << 6];

        for (int i = 0; i < rs; ++i) {
            float b0 = 0.0f, b1 = 0.0f; int tgn = 0;
            if (i + 1 < rs) {                          // wave-uniform
                const float* nxt = rowp + NC;
                b0  = nxt[lane];
                b1  = nxt[17 + lane];
                tgn = tgt_s[(wave << 6) + i + 1];
            }
            float e = __expf(a0) + ((lane >= 47) ? __expf(a1) : 0.0f);
            #pragma unroll
            for (int o = 32; o; o >>= 1) e += __shfl_xor(e, o, 64);
            float tv = (tg < 64) ? __shfl(a0, tg, 64)
                                 : __shfl(a1, tg - 17, 64);
            float cev = __logf(e) - tv;
            if (lane == i) {                           // keep row i's CE in lane i
                v_ce = cev;
                if (tg > 0) sp += cev; else sn += cev;
            }
            a0 = b0; a1 = b1; tg = tgn; rowp += NC;
        }
        if (lane < rs)
            ce[(size_t)b * NP + (size_t)(rbase + lane)] = v_ce;
    }

    // ---- block reduce 5 values -> atomics ----
    float vnp = (float)np;
    #pragma unroll
    for (int o = 32; o; o >>= 1) {
        l_sum += __shfl_xor(l_sum, o, 64);
        f_sum += __shfl_xor(f_sum, o, 64);
        sp    += __shfl_xor(sp, o, 64);
        sn    += __shfl_xor(sn, o, 64);
        vnp   += __shfl_xor(vnp, o, 64);
    }
    if (lane == 0) {
        red[wave][0] = l_sum; red[wave][1] = f_sum;
        red[wave][2] = sp;    red[wave][3] = sn;   red[wave][4] = vnp;
    }
    __syncthreads();
    if (t == 0) {
        float rl = 0, rf = 0, rp = 0, rn = 0, rc = 0;
        #pragma unroll
        for (int w = 0; w < 4; ++w) {
            rl += red[w][0]; rf += red[w][1]; rp += red[w][2];
            rn += red[w][3]; rc += red[w][4];
        }
        atomicAdd(&acc[0], rl);
        atomicAdd(&acc[1], rf);
        atomicAdd(&spos_b[b], rp);
        atomicAdd(&sneg_b[b], rn);
        atomicAdd(&npos_b[b], (int)rc);
    }
}

// One block per batch. Common path: O(1). Rare path: top-K via bit binary search.
__global__ __launch_bounds__(256) void k_batch(
    const float* __restrict__ ce, const int* __restrict__ conf_t,
    const int* __restrict__ npos_b, const float* __restrict__ spos_b,
    const float* __restrict__ sneg_b, float* __restrict__ loss_c_b)
{
    const int b = blockIdx.x;
    const int t = threadIdx.x;
    const int npos    = npos_b[b];
    const int nneg    = NP - npos;
    const int num_neg = min(3 * npos, NP - 1);

    if (num_neg >= nneg) {              // all negatives selected (this dataset)
        if (t == 0) loss_c_b[b] = spos_b[b] + sneg_b[b];
        return;
    }
    if (num_neg <= 0) {
        if (t == 0) loss_c_b[b] = spos_b[b];
        return;
    }

    // general path: stage negative CE into LDS (positives -> -1), top-K sum
    __shared__ float ce_s[NP];
    __shared__ float sredf[4];
    __shared__ int   sredi[4];
    const float* crow = ce + (size_t)b * NP;
    const int*   trow = conf_t + (size_t)b * NP;
    for (int p = t; p < NP; p += 256)
        ce_s[p] = (trow[p] > 0) ? -1.0f : crow[p];
    __syncthreads();

    const int wave = t >> 6, lane = t & 63;
    const int K = num_neg;
    unsigned lo = 0u, hi = 0x7f800000u;
    while (lo < hi) {
        unsigned mid = lo + ((hi - lo) >> 1);
        float v = __uint_as_float(mid);
        int c_t = 0;
        for (int p = t; p < NP; p += 256) c_t += (ce_s[p] > v) ? 1 : 0;
        #pragma unroll
        for (int o = 32; o; o >>= 1) c_t += __shfl_xor(c_t, o, 64);
        __syncthreads();
        if (lane == 0) sredi[wave] = c_t;
        __syncthreads();
        int cnt = sredi[0] + sredi[1] + sredi[2] + sredi[3];
        if (cnt < K) hi = mid; else lo = mid + 1;
    }
    float v = __uint_as_float(lo);       // K-th largest negative CE
    int c_t = 0; float s_t = 0.0f;
    for (int p = t; p < NP; p += 256) {
        float x = ce_s[p];
        if (x > v) { c_t++; s_t += x; }
    }
    #pragma unroll
    for (int o = 32; o; o >>= 1) {
        c_t += __shfl_xor(c_t, o, 64);
        s_t += __shfl_xor(s_t, o, 64);
    }
    __syncthreads();
    if (lane == 0) { sredi[wave] = c_t; sredf[wave] = s_t; }
    __syncthreads();
    if (t == 0) {
        int   cnt = sredi[0] + sredi[1] + sredi[2] + sredi[3];
        float sgt = sredf[0] + sredf[1] + sredf[2] + sredf[3];
        loss_c_b[b] = spos_b[b] + sgt + (float)(K - cnt) * v;
    }
}

__global__ void k_final(const float* __restrict__ acc,
                        const float* __restrict__ loss_c_b,
                        const int* __restrict__ npos_b,
                        float* __restrict__ out)
{
    const int t = threadIdx.x;           // 64 threads
    float lc = loss_c_b[t];
    int   np = npos_b[t];
    #pragma unroll
    for (int o = 32; o; o >>= 1) {
        lc += __shfl_xor(lc, o, 64);
        np += __shfl_xor(np, o, 64);
    }
    if (t == 0) {
        float N = (float)np;
        out[0] = acc[0] / N;
        out[1] = lc / N;
        out[2] = acc[1] / N;
    }
}

extern "C" void kernel_launch(void* const* d_in, const int* in_sizes, int n_in,
                              void* d_out, int out_size, void* d_ws, size_t ws_size,
                              hipStream_t stream)
{
    const float* loc_data  = (const float*)d_in[0];
    const float* conf_data = (const float*)d_in[1];
    const float* fc_data   = (const float*)d_in[2];
    const float* loc_t     = (const float*)d_in[3];
    const float* fc_t      = (const float*)d_in[4];
    const int*   conf_t    = (const int*)d_in[5];
    float* out = (float*)d_out;

    float* ce       = (float*)d_ws;
    float* acc      = ce + BP;           // [2]
    int*   npos_b   = (int*)(acc + 2);   // [64]
    float* spos_b   = (float*)(npos_b + 64);
    float* sneg_b   = spos_b + 64;
    float* loss_c_b = sneg_b + 64;

    hipLaunchKernelGGL(k_init,  dim3(1), dim3(256), 0, stream, acc);
    hipLaunchKernelGGL(k_main,  dim3(PBLK, NB), dim3(256), 0, stream,
                       loc_data, conf_data, fc_data, loc_t, fc_t, conf_t,
                       ce, acc, npos_b, spos_b, sneg_b);
    hipLaunchKernelGGL(k_batch, dim3(NB), dim3(256), 0, stream,
                       ce, conf_t, npos_b, spos_b, sneg_b, loss_c_b);
    hipLaunchKernelGGL(k_final, dim3(1), dim3(64), 0, stream,
                       acc, loss_c_b, npos_b, out);
}

// Round 4
// 320.647 us; speedup vs baseline: 1.2293x; 1.2293x over previous
//
#include <hip/hip_runtime.h>

// MultiBoxLoss_four_corners — B=64, P=8732, C=81, NEG_POS_RATIO=3
// Outputs: (loss_l/N, loss_c/N, loss_four_corners/N) -> d_out[0..2] (f32)
//
// R6: bottleneck identified as L1 transaction processing (line-touches/row):
// R2 thread-per-row scalar = 81 touches/row (107us); R5 wave-per-row fixed
// touches but serialized on 8-deep shfl chain (188us). Now: 4 LANES PER ROW,
// 6x global_load_dwordx4 per row (16 rows/wave-instr, ~64B contiguous per
// row -> ~10 touches/row), out-of-row elems masked, 2-shfl reduce, scalar
// row[tgt] load. No LDS staging, no barriers, 16 rows in flight per wave.

#define NB 64
#define NP 8732
#define NC 81
constexpr int BP = NB * NP;              // 558848
constexpr int PBLK = (NP + 255) / 256;   // 35 blocks per batch (tail 28)
constexpr unsigned MAXCH = (unsigned)((size_t)BP * NC / 4 - 1);  // 11316671

__device__ inline float sl1(float d) {
    d = fabsf(d);
    return d < 1.0f ? 0.5f * d * d : d - 0.5f;
}

// ws layout: ce[BP] | acc[2] | npos_b[64](int) | spos_b[64] | sneg_b[64] | loss_c_b[64]
__global__ void k_init(float* acc_area) {
    if (threadIdx.x < 194) acc_area[threadIdx.x] = 0.0f;
}

__global__ __launch_bounds__(256) void k_main(
    const float* __restrict__ loc_data, const float* __restrict__ conf_data,
    const float* __restrict__ fc_data,  const float* __restrict__ loc_t,
    const float* __restrict__ fc_t,     const int* __restrict__ conf_t,
    float* __restrict__ ce, float* __restrict__ acc,
    int* __restrict__ npos_b, float* __restrict__ spos_b, float* __restrict__ sneg_b)
{
    const int b  = blockIdx.y;
    const int t  = threadIdx.x;
    const int p0 = blockIdx.x << 8;

    __shared__ int   tgt_s[256];
    __shared__ float red[4][5];

    float l_sum = 0.0f, f_sum = 0.0f, sp = 0.0f, sn = 0.0f;
    int np = 0;

    // ---- per-prior smooth-L1 (coalesced float4) + stash targets ----
    {
        const int p = p0 + t;
        int tgt = 0;
        if (p < NP) {
            const size_t g = (size_t)b * NP + p;
            tgt = conf_t[g];
            const float posf = (tgt > 0) ? 1.0f : 0.0f;
            np = (tgt > 0) ? 1 : 0;
            float4 a4  = ((const float4*)loc_data)[g];
            float4 a4t = ((const float4*)loc_t)[g];
            l_sum = (sl1(a4.x - a4t.x) + sl1(a4.y - a4t.y) +
                     sl1(a4.z - a4t.z) + sl1(a4.w - a4t.w)) * posf;
            float4 c0 = ((const float4*)fc_data)[2 * g];
            float4 c1 = ((const float4*)fc_data)[2 * g + 1];
            float4 d0 = ((const float4*)fc_t)[2 * g];
            float4 d1 = ((const float4*)fc_t)[2 * g + 1];
            f_sum = (sl1(c0.x - d0.x) + sl1(c0.y - d0.y) + sl1(c0.z - d0.z) + sl1(c0.w - d0.w) +
                     sl1(c1.x - d1.x) + sl1(c1.y - d1.y) + sl1(c1.z - d1.z) + sl1(c1.w - d1.w)) * posf;
        }
        tgt_s[t] = tgt;
    }
    __syncthreads();

    // ---- CE: 4 lanes per row, direct float4 loads ----
    const int wave = t >> 6, lane = t & 63;
    const int grp = lane >> 2, sub = lane & 3;
    const float4* conf4 = (const float4*)conf_data;

    #pragma unroll 1
    for (int s = 0; s < 4; ++s) {
        const int pl = (wave << 6) + (s << 4) + grp;   // [0,256)
        const int p  = p0 + pl;
        const int pe = min(p, NP - 1);                 // clamp tail reads
        const unsigned g  = (unsigned)b * NP + (unsigned)pe;   // <= 558847
        const unsigned fb = g * (unsigned)NC;          // <= 45266607
        const int al      = (int)(fb & 3u);
        const unsigned c0 = fb >> 2;

        const int tgt = tgt_s[pl];
        float tv = 0.0f;
        if (sub == 0) tv = conf_data[fb + (unsigned)tgt];   // early, L1-hit

        float e = 0.0f;
        #pragma unroll
        for (int k = 0; k < 6; ++k) {
            unsigned ch = c0 + (unsigned)(sub + 4 * k);
            ch = ch > MAXCH ? MAXCH : ch;              // tensor-end clamp
            const float4 v = conf4[ch];
            const int bi = 4 * (sub + 4 * k) - al;     // row elem of v.x
            e += ((unsigned)(bi + 0) < 81u) ? __expf(v.x) : 0.0f;
            e += ((unsigned)(bi + 1) < 81u) ? __expf(v.y) : 0.0f;
            e += ((unsigned)(bi + 2) < 81u) ? __expf(v.z) : 0.0f;
            e += ((unsigned)(bi + 3) < 81u) ? __expf(v.w) : 0.0f;
        }
        e += __shfl_xor(e, 1, 64);                     // 4-lane group sum
        e += __shfl_xor(e, 2, 64);

        if (sub == 0 && p < NP) {
            const float cev = __logf(e) - tv;
            ce[g] = cev;
            if (tgt > 0) sp += cev; else sn += cev;
        }
    }

    // ---- block reduce 5 values -> atomics ----
    float vnp = (float)np;
    #pragma unroll
    for (int o = 32; o; o >>= 1) {
        l_sum += __shfl_xor(l_sum, o, 64);
        f_sum += __shfl_xor(f_sum, o, 64);
        sp    += __shfl_xor(sp, o, 64);
        sn    += __shfl_xor(sn, o, 64);
        vnp   += __shfl_xor(vnp, o, 64);
    }
    if (lane == 0) {
        red[wave][0] = l_sum; red[wave][1] = f_sum;
        red[wave][2] = sp;    red[wave][3] = sn;   red[wave][4] = vnp;
    }
    __syncthreads();
    if (t == 0) {
        float rl = 0, rf = 0, rp = 0, rn = 0, rc = 0;
        #pragma unroll
        for (int w = 0; w < 4; ++w) {
            rl += red[w][0]; rf += red[w][1]; rp += red[w][2];
            rn += red[w][3]; rc += red[w][4];
        }
        atomicAdd(&acc[0], rl);
        atomicAdd(&acc[1], rf);
        atomicAdd(&spos_b[b], rp);
        atomicAdd(&sneg_b[b], rn);
        atomicAdd(&npos_b[b], (int)rc);
    }
}

// One block per batch. Common path: O(1). Rare path: top-K via bit binary search.
__global__ __launch_bounds__(256) void k_batch(
    const float* __restrict__ ce, const int* __restrict__ conf_t,
    const int* __restrict__ npos_b, const float* __restrict__ spos_b,
    const float* __restrict__ sneg_b, float* __restrict__ loss_c_b)
{
    const int b = blockIdx.x;
    const int t = threadIdx.x;
    const int npos    = npos_b[b];
    const int nneg    = NP - npos;
    const int num_neg = min(3 * npos, NP - 1);

    if (num_neg >= nneg) {              // all negatives selected (this dataset)
        if (t == 0) loss_c_b[b] = spos_b[b] + sneg_b[b];
        return;
    }
    if (num_neg <= 0) {
        if (t == 0) loss_c_b[b] = spos_b[b];
        return;
    }

    // general path: stage negative CE into LDS (positives -> -1), top-K sum
    __shared__ float ce_s[NP];
    __shared__ float sredf[4];
    __shared__ int   sredi[4];
    const float* crow = ce + (size_t)b * NP;
    const int*   trow = conf_t + (size_t)b * NP;
    for (int p = t; p < NP; p += 256)
        ce_s[p] = (trow[p] > 0) ? -1.0f : crow[p];
    __syncthreads();

    const int wave = t >> 6, lane = t & 63;
    const int K = num_neg;
    unsigned lo = 0u, hi = 0x7f800000u;
    while (lo < hi) {
        unsigned mid = lo + ((hi - lo) >> 1);
        float v = __uint_as_float(mid);
        int c_t = 0;
        for (int p = t; p < NP; p += 256) c_t += (ce_s[p] > v) ? 1 : 0;
        #pragma unroll
        for (int o = 32; o; o >>= 1) c_t += __shfl_xor(c_t, o, 64);
        __syncthreads();
        if (lane == 0) sredi[wave] = c_t;
        __syncthreads();
        int cnt = sredi[0] + sredi[1] + sredi[2] + sredi[3];
        if (cnt < K) hi = mid; else lo = mid + 1;
    }
    float v = __uint_as_float(lo);       // K-th largest negative CE
    int c_t = 0; float s_t = 0.0f;
    for (int p = t; p < NP; p += 256) {
        float x = ce_s[p];
        if (x > v) { c_t++; s_t += x; }
    }
    #pragma unroll
    for (int o = 32; o; o >>= 1) {
        c_t += __shfl_xor(c_t, o, 64);
        s_t += __shfl_xor(s_t, o, 64);
    }
    __syncthreads();
    if (lane == 0) { sredi[wave] = c_t; sredf[wave] = s_t; }
    __syncthreads();
    if (t == 0) {
        int   cnt = sredi[0] + sredi[1] + sredi[2] + sredi[3];
        float sgt = sredf[0] + sredf[1] + sredf[2] + sredf[3];
        loss_c_b[b] = spos_b[b] + sgt + (float)(K - cnt) * v;
    }
}

__global__ void k_final(const float* __restrict__ acc,
                        const float* __restrict__ loss_c_b,
                        const int* __restrict__ npos_b,
                        float* __restrict__ out)
{
    const int t = threadIdx.x;           // 64 threads
    float lc = loss_c_b[t];
    int   np = npos_b[t];
    #pragma unroll
    for (int o = 32; o; o >>= 1) {
        lc += __shfl_xor(lc, o, 64);
        np += __shfl_xor(np, o, 64);
    }
    if (t == 0) {
        float N = (float)np;
        out[0] = acc[0] / N;
        out[1] = lc / N;
        out[2] = acc[1] / N;
    }
}

extern "C" void kernel_launch(void* const* d_in, const int* in_sizes, int n_in,
                              void* d_out, int out_size, void* d_ws, size_t ws_size,
                              hipStream_t stream)
{
    const float* loc_data  = (const float*)d_in[0];
    const float* conf_data = (const float*)d_in[1];
    const float* fc_data   = (const float*)d_in[2];
    const float* loc_t     = (const float*)d_in[3];
    const float* fc_t      = (const float*)d_in[4];
    const int*   conf_t    = (const int*)d_in[5];
    float* out = (float*)d_out;

    float* ce       = (float*)d_ws;
    float* acc      = ce + BP;           // [2]
    int*   npos_b   = (int*)(acc + 2);   // [64]
    float* spos_b   = (float*)(npos_b + 64);
    float* sneg_b   = spos_b + 64;
    float* loss_c_b = sneg_b + 64;

    hipLaunchKernelGGL(k_init,  dim3(1), dim3(256), 0, stream, acc);
    hipLaunchKernelGGL(k_main,  dim3(PBLK, NB), dim3(256), 0, stream,
                       loc_data, conf_data, fc_data, loc_t, fc_t, conf_t,
                       ce, acc, npos_b, spos_b, sneg_b);
    hipLaunchKernelGGL(k_batch, dim3(NB), dim3(256), 0, stream,
                       ce, conf_t, npos_b, spos_b, sneg_b, loss_c_b);
    hipLaunchKernelGGL(k_final, dim3(1), dim3(64), 0, stream,
                       acc, loss_c_b, npos_b, out);
}